// Round 15
// baseline (294.958 us; speedup 1.0000x reference)
//
#include <hip/hip_runtime.h>
#include <math.h>

#define F_OUT 128
#define MAXDEG 64

typedef __attribute__((ext_vector_type(8))) short short8v;   // 8 bf16 (4 VGPR)
typedef __attribute__((ext_vector_type(4))) float f32x4;
typedef unsigned long long ull;

// ---- manual RNE fp32->bf16 (self-contained, finite inputs) ----
__device__ inline ushort f2bf(float x) {
    uint u = __float_as_uint(x);
    uint r = (u + 0x7FFFu + ((u >> 16) & 1u)) >> 16;
    return (ushort)r;
}
__device__ inline float bf2f(ushort h) { return __uint_as_float((uint)h << 16); }
__device__ inline uint pack2(ushort a, ushort b) { return (uint)a | ((uint)b << 16); }

__device__ inline float slot_sumw(ull s) {
    return (float)((double)(s & ((1ull << 40) - 1)) * (1.0 / 8388608.0));
}

// ---------------- prep: wsplit(W1) || zero(slot) ----------------

__global__ __launch_bounds__(128) void prep_kernel(const float* __restrict__ W1,
                                                   ushort* W1th, ushort* W1tl,
                                                   ull* slot, int n) {
    int b = blockIdx.x;
    if (b < 256) {                    // W1 split: 256*128 = 32768 elems
        int idx = b * 128 + threadIdx.x;
        int k = idx >> 7, c = idx & 127;
        float x = W1[idx];
        ushort h = f2bf(x);
        ushort l = f2bf(x - bf2f(h));
        W1th[(size_t)c * 256 + k] = h;
        W1tl[(size_t)c * 256 + k] = l;
    } else {
        int i = (b - 256) * 128 + threadIdx.x;
        if (i < n) slot[i] = 0ull;
    }
}

// ---------------- fill: one 64-bit atomic per edge ----------------
// slot[d] = (count << 40) | sum(w * 2^23)

__device__ __forceinline__ void fill_edge(const int* __restrict__ src,
                                          const int* __restrict__ dst,
                                          const float* __restrict__ w,
                                          ull* slot, int2* es, int e) {
    int s = src[e], d = dst[e];
    float wv = w[e];
    ull inc = (1ull << 40) | (ull)(uint)(wv * 8388608.0f + 0.5f);
    ull old = atomicAdd(&slot[d], inc);
    uint pos = (uint)(old >> 40);
    if (pos < MAXDEG) es[(size_t)d * MAXDEG + pos] = make_int2(s, __float_as_int(wv));
}

// coef: es.y = dis[src] * w, dis computed on the fly from slot
__global__ void coef_kernel(int2* es, const ull* __restrict__ slot, int n) {
    int i = blockIdx.x * blockDim.x + threadIdx.x;
    if (i < n * MAXDEG) {
        int d = i >> 6;                 // MAXDEG = 64
        int pos = i & (MAXDEG - 1);
        int cnt = (int)(slot[d] >> 40);
        if (pos < cnt) {
            int2 e = es[i];
            float dsrc = rsqrtf(1.0f + slot_sumw(slot[e.x]));
            es[i].y = __float_as_int(dsrc * __int_as_float(e.y));
        }
    }
}

// ---------------- gather-one-node helper ----------------
// returns relu(bias + dd*(dd_selfterm... caller passes via hin[node]) ...)
// acc = dd * (h[node] + sum_e coef_e * h[src]);  out = relu(bias + acc)
// (h[node]'s dd factor is folded: acc starts at dd*h[node] -> then *dd at end
//  matches: dd*(dd*h[d] + sum coef*h[s]) since coef already has dis_src.)

__device__ __forceinline__ void gacc(uint u, float c, float& ax, float& ay) {
    ax += c * __uint_as_float(u << 16);
    ay += c * __uint_as_float(u & 0xFFFF0000u);
}

__device__ __forceinline__ float2 gather_node(const ushort* __restrict__ hin,
                                              const int2* __restrict__ ep,
                                              int cnt, float dd, int node, int f,
                                              float bx, float by) {
    uint hv = *reinterpret_cast<const uint*>(&hin[(size_t)node * F_OUT + f]);
    float accx = dd * __uint_as_float(hv << 16);
    float accy = dd * __uint_as_float(hv & 0xFFFF0000u);

    int i = 0;
    for (; i + 15 < cnt; i += 16) {
        int4 p[8];
        #pragma unroll
        for (int q = 0; q < 8; ++q) p[q] = *reinterpret_cast<const int4*>(&ep[i + 2 * q]);
        uint u[16];
        #pragma unroll
        for (int q = 0; q < 8; ++q) {
            u[2 * q]     = *reinterpret_cast<const uint*>(&hin[(size_t)p[q].x * F_OUT + f]);
            u[2 * q + 1] = *reinterpret_cast<const uint*>(&hin[(size_t)p[q].z * F_OUT + f]);
        }
        #pragma unroll
        for (int q = 0; q < 8; ++q) {
            gacc(u[2 * q],     __int_as_float(p[q].y), accx, accy);
            gacc(u[2 * q + 1], __int_as_float(p[q].w), accx, accy);
        }
    }
    for (; i + 7 < cnt; i += 8) {
        int4 p01 = *reinterpret_cast<const int4*>(&ep[i]);
        int4 p23 = *reinterpret_cast<const int4*>(&ep[i + 2]);
        int4 p45 = *reinterpret_cast<const int4*>(&ep[i + 4]);
        int4 p67 = *reinterpret_cast<const int4*>(&ep[i + 6]);
        uint u0 = *reinterpret_cast<const uint*>(&hin[(size_t)p01.x * F_OUT + f]);
        uint u1 = *reinterpret_cast<const uint*>(&hin[(size_t)p01.z * F_OUT + f]);
        uint u2 = *reinterpret_cast<const uint*>(&hin[(size_t)p23.x * F_OUT + f]);
        uint u3 = *reinterpret_cast<const uint*>(&hin[(size_t)p23.z * F_OUT + f]);
        uint u4 = *reinterpret_cast<const uint*>(&hin[(size_t)p45.x * F_OUT + f]);
        uint u5 = *reinterpret_cast<const uint*>(&hin[(size_t)p45.z * F_OUT + f]);
        uint u6 = *reinterpret_cast<const uint*>(&hin[(size_t)p67.x * F_OUT + f]);
        uint u7 = *reinterpret_cast<const uint*>(&hin[(size_t)p67.z * F_OUT + f]);
        gacc(u0, __int_as_float(p01.y), accx, accy);
        gacc(u1, __int_as_float(p01.w), accx, accy);
        gacc(u2, __int_as_float(p23.y), accx, accy);
        gacc(u3, __int_as_float(p23.w), accx, accy);
        gacc(u4, __int_as_float(p45.y), accx, accy);
        gacc(u5, __int_as_float(p45.w), accx, accy);
        gacc(u6, __int_as_float(p67.y), accx, accy);
        gacc(u7, __int_as_float(p67.w), accx, accy);
    }
    for (; i + 1 < cnt; i += 2) {
        int4 p01 = *reinterpret_cast<const int4*>(&ep[i]);
        uint u0 = *reinterpret_cast<const uint*>(&hin[(size_t)p01.x * F_OUT + f]);
        uint u1 = *reinterpret_cast<const uint*>(&hin[(size_t)p01.z * F_OUT + f]);
        gacc(u0, __int_as_float(p01.y), accx, accy);
        gacc(u1, __int_as_float(p01.w), accx, accy);
    }
    if (i < cnt) {
        int2 e0 = ep[i];
        uint u0 = *reinterpret_cast<const uint*>(&hin[(size_t)e0.x * F_OUT + f]);
        gacc(u0, __int_as_float(e0.y), accx, accy);
    }

    float2 r;
    r.x = fmaxf(bx + dd * accx, 0.f);
    r.y = fmaxf(by + dd * accy, 0.f);
    return r;
}

// ---------------- GEMM body (layer 1): fp32 in, split in-kernel ----------------
// Split-bf16 3-product (hh + hl + lh), fp32 accumulate, bf16 output.
// BM=64, BN=128, BK=32; 128 threads = 2 waves; chunk-major LDS (conflict-free).

template <int K>
__device__ __forceinline__ void gemm_body(ushort* sAh, ushort* sAl,
                                          ushort* sBh, ushort* sBl,
                                          const float* __restrict__ in,
                                          const ushort* __restrict__ Wth,
                                          const ushort* __restrict__ Wtl,
                                          ushort* __restrict__ hbf, int n, int bb) {
    const int t = threadIdx.x;
    const int lane = t & 63;
    const int wv = t >> 6;
    const int block_row = bb * 64;

    const int arow = t >> 1;
    const int ahalf = t & 1;
    const int bcol = t;

    const int l15 = lane & 15;
    const int koct = lane >> 4;

    f32x4 acc[4][4];
    #pragma unroll
    for (int r = 0; r < 4; ++r)
        #pragma unroll
        for (int c = 0; c < 4; ++c) acc[r][c] = (f32x4){0.f, 0.f, 0.f, 0.f};

    const int grow_a = block_row + arow;
    const bool arow_ok = grow_a < n;

    for (int kt = 0; kt < K / 32; ++kt) {
        const int k0 = kt * 32;

        {
            float v[16];
            if (arow_ok) {
                const float4* p = reinterpret_cast<const float4*>(
                    &in[(size_t)grow_a * K + k0 + ahalf * 16]);
                float4 f0 = p[0], f1 = p[1], f2 = p[2], f3 = p[3];
                v[0]=f0.x; v[1]=f0.y; v[2]=f0.z; v[3]=f0.w;
                v[4]=f1.x; v[5]=f1.y; v[6]=f1.z; v[7]=f1.w;
                v[8]=f2.x; v[9]=f2.y; v[10]=f2.z; v[11]=f2.w;
                v[12]=f3.x; v[13]=f3.y; v[14]=f3.z; v[15]=f3.w;
            } else {
                #pragma unroll
                for (int i = 0; i < 16; ++i) v[i] = 0.f;
            }
            ushort hh[16], ll[16];
            #pragma unroll
            for (int i = 0; i < 16; ++i) {
                hh[i] = f2bf(v[i]);
                ll[i] = f2bf(v[i] - bf2f(hh[i]));
            }
            const int c0 = 2 * ahalf, c1 = 2 * ahalf + 1;
            *reinterpret_cast<uint4*>(&sAh[(c0 * 64 + arow) * 8]) =
                make_uint4(pack2(hh[0],hh[1]), pack2(hh[2],hh[3]), pack2(hh[4],hh[5]), pack2(hh[6],hh[7]));
            *reinterpret_cast<uint4*>(&sAh[(c1 * 64 + arow) * 8]) =
                make_uint4(pack2(hh[8],hh[9]), pack2(hh[10],hh[11]), pack2(hh[12],hh[13]), pack2(hh[14],hh[15]));
            *reinterpret_cast<uint4*>(&sAl[(c0 * 64 + arow) * 8]) =
                make_uint4(pack2(ll[0],ll[1]), pack2(ll[2],ll[3]), pack2(ll[4],ll[5]), pack2(ll[6],ll[7]));
            *reinterpret_cast<uint4*>(&sAl[(c1 * 64 + arow) * 8]) =
                make_uint4(pack2(ll[8],ll[9]), pack2(ll[10],ll[11]), pack2(ll[12],ll[13]), pack2(ll[14],ll[15]));
        }
        {
            const uint4* ph = reinterpret_cast<const uint4*>(&Wth[(size_t)bcol * K + k0]);
            const uint4* pl = reinterpret_cast<const uint4*>(&Wtl[(size_t)bcol * K + k0]);
            #pragma unroll
            for (int j = 0; j < 4; ++j)
                *reinterpret_cast<uint4*>(&sBh[(j * 128 + bcol) * 8]) = ph[j];
            #pragma unroll
            for (int j = 0; j < 4; ++j)
                *reinterpret_cast<uint4*>(&sBl[(j * 128 + bcol) * 8]) = pl[j];
        }
        __syncthreads();

        short8v a_h[4], a_l[4], b_h[4], b_l[4];
        #pragma unroll
        for (int r = 0; r < 4; ++r) {
            a_h[r] = *reinterpret_cast<const short8v*>(&sAh[(koct * 64 + r * 16 + l15) * 8]);
            a_l[r] = *reinterpret_cast<const short8v*>(&sAl[(koct * 64 + r * 16 + l15) * 8]);
        }
        #pragma unroll
        for (int c = 0; c < 4; ++c) {
            b_h[c] = *reinterpret_cast<const short8v*>(&sBh[(koct * 128 + wv * 64 + c * 16 + l15) * 8]);
            b_l[c] = *reinterpret_cast<const short8v*>(&sBl[(koct * 128 + wv * 64 + c * 16 + l15) * 8]);
        }
        #pragma unroll
        for (int r = 0; r < 4; ++r)
            #pragma unroll
            for (int c = 0; c < 4; ++c) {
                acc[r][c] = __builtin_amdgcn_mfma_f32_16x16x32_bf16(a_h[r], b_h[c], acc[r][c], 0, 0, 0);
                acc[r][c] = __builtin_amdgcn_mfma_f32_16x16x32_bf16(a_h[r], b_l[c], acc[r][c], 0, 0, 0);
                acc[r][c] = __builtin_amdgcn_mfma_f32_16x16x32_bf16(a_l[r], b_h[c], acc[r][c], 0, 0, 0);
            }
        __syncthreads();
    }

    // ---- epilogue: bf16 store ----
    #pragma unroll
    for (int r = 0; r < 4; ++r) {
        #pragma unroll
        for (int c = 0; c < 4; ++c) {
            int gcol = wv * 64 + c * 16 + l15;
            #pragma unroll
            for (int j = 0; j < 4; ++j) {
                int grow = block_row + r * 16 + koct * 4 + j;
                if (grow < n) hbf[(size_t)grow * F_OUT + gcol] = f2bf(acc[r][c][j]);
            }
        }
    }
}

// ---------------- mega1: GEMM1 || fill(1 edge/thread) || wsplit(W2,W3) ----------------

__global__ __launch_bounds__(128) void mega1_kernel(
        const float* __restrict__ x,
        const ushort* __restrict__ W1th, const ushort* __restrict__ W1tl,
        ushort* __restrict__ hbf,
        const int* __restrict__ src, const int* __restrict__ dst,
        const float* __restrict__ w, ull* slot, int2* es,
        const float* __restrict__ W2, ushort* W2th, ushort* W2tl,
        const float* __restrict__ W3, ushort* W3th, ushort* W3tl,
        int n, int E, int GB, int FB) {
    __shared__ ushort sAh[64 * 32], sAl[64 * 32];
    __shared__ ushort sBh[128 * 32], sBl[128 * 32];

    int b = blockIdx.x;
    if (b < GB) {
        gemm_body<256>(sAh, sAl, sBh, sBl, x, W1th, W1tl, hbf, n, b);
    } else if (b < GB + FB) {
        int e = (b - GB) * 128 + threadIdx.x;
        if (e < E) fill_edge(src, dst, w, slot, es, e);
    } else {
        int wb = b - GB - FB;          // 0..255: W2 then W3 (16384 elems each)
        const float* W = (wb < 128) ? W2 : W3;
        ushort* Th = (wb < 128) ? W2th : W3th;
        ushort* Tl = (wb < 128) ? W2tl : W3tl;
        int idx = (wb & 127) * 128 + threadIdx.x;
        int k = idx >> 7, c = idx & 127;
        float v = W[idx];
        ushort h = f2bf(v);
        ushort l = f2bf(v - bf2f(h));
        Th[(size_t)c * 128 + k] = h;
        Tl[(size_t)c * 128 + k] = l;
    }
}

// ---------------- fused gather+GEMM (layers 2,3) ----------------
// Per block: gather 64 nodes of layer-i output (bias+relu) -> split-bf16
// A-tile directly in LDS -> MFMA with W_{i+1} -> write raw h_{i+1} (bf16).
// 256 threads = 4 waves. A LDS: [16 chunks][65 rows pad][8] (conflict-safe).
// B LDS: [4 chunks][128 cols][8] per 32-k slice.

#define AROWS 65   // 64 + 1 pad: chunk stride 1040B -> 4-bank shift per chunk

__global__ __launch_bounds__(256) void fused_gg(
        const ushort* __restrict__ hin,
        const int2* __restrict__ es,
        const ull* __restrict__ slot,
        const float* __restrict__ bias,
        const ushort* __restrict__ Wth, const ushort* __restrict__ Wtl,
        ushort* __restrict__ hout, int n) {
    __shared__ ushort sAh[16 * AROWS * 8], sAl[16 * AROWS * 8];
    __shared__ ushort sBh[4 * 128 * 8],    sBl[4 * 128 * 8];

    const int t = threadIdx.x;
    const int wv = t >> 6;            // 0..3
    const int lane = t & 63;
    const int block_row = blockIdx.x * 64;
    const int f = lane * 2;

    // ---- phase 1: gather 16 nodes per wave -> split-bf16 A tile in LDS ----
    {
        const float bx = bias[f], by = bias[f + 1];
        const int chunk = f >> 3;          // 0..15
        const int fo = f & 7;
        for (int it = 0; it < 16; ++it) {
            int nl = wv * 16 + it;         // 0..63
            int node = block_row + nl;
            float2 r = make_float2(0.f, 0.f);
            if (node < n) {
                ull sl = slot[node];
                int cnt = (int)(sl >> 40);
                if (cnt > MAXDEG) cnt = MAXDEG;
                float dd = rsqrtf(1.0f + slot_sumw(sl));
                r = gather_node(hin, es + (size_t)node * MAXDEG, cnt, dd, node, f, bx, by);
            }
            ushort hx = f2bf(r.x), hy = f2bf(r.y);
            ushort lx = f2bf(r.x - bf2f(hx)), ly = f2bf(r.y - bf2f(hy));
            int off = (chunk * AROWS + nl) * 8 + fo;
            *reinterpret_cast<uint*>(&sAh[off]) = pack2(hx, hy);
            *reinterpret_cast<uint*>(&sAl[off]) = pack2(lx, ly);
        }
    }
    __syncthreads();

    // ---- phase 2: MFMA over K=128 ----
    const int l15 = lane & 15;
    const int koct = lane >> 4;
    f32x4 acc[4][2];
    #pragma unroll
    for (int r = 0; r < 4; ++r)
        #pragma unroll
        for (int c = 0; c < 2; ++c) acc[r][c] = (f32x4){0.f, 0.f, 0.f, 0.f};

    const int bcol = t & 127;
    const int jh = (t >> 7) * 2;       // 0 or 2

    for (int kt = 0; kt < 4; ++kt) {
        // stage B 32-k slice (2 chunks per thread)
        {
            const uint4* ph = reinterpret_cast<const uint4*>(&Wth[(size_t)bcol * 128 + kt * 32 + jh * 8]);
            const uint4* pl = reinterpret_cast<const uint4*>(&Wtl[(size_t)bcol * 128 + kt * 32 + jh * 8]);
            *reinterpret_cast<uint4*>(&sBh[(jh * 128 + bcol) * 8])       = ph[0];
            *reinterpret_cast<uint4*>(&sBh[((jh + 1) * 128 + bcol) * 8]) = ph[1];
            *reinterpret_cast<uint4*>(&sBl[(jh * 128 + bcol) * 8])       = pl[0];
            *reinterpret_cast<uint4*>(&sBl[((jh + 1) * 128 + bcol) * 8]) = pl[1];
        }
        __syncthreads();

        short8v a_h[4], a_l[4], b_h[2], b_l[2];
        #pragma unroll
        for (int r = 0; r < 4; ++r) {
            int off = (((kt * 4 + koct) * AROWS) + r * 16 + l15) * 8;
            a_h[r] = *reinterpret_cast<const short8v*>(&sAh[off]);
            a_l[r] = *reinterpret_cast<const short8v*>(&sAl[off]);
        }
        #pragma unroll
        for (int c = 0; c < 2; ++c) {
            int off = (koct * 128 + wv * 32 + c * 16 + l15) * 8;
            b_h[c] = *reinterpret_cast<const short8v*>(&sBh[off]);
            b_l[c] = *reinterpret_cast<const short8v*>(&sBl[off]);
        }
        #pragma unroll
        for (int r = 0; r < 4; ++r)
            #pragma unroll
            for (int c = 0; c < 2; ++c) {
                acc[r][c] = __builtin_amdgcn_mfma_f32_16x16x32_bf16(a_h[r], b_h[c], acc[r][c], 0, 0, 0);
                acc[r][c] = __builtin_amdgcn_mfma_f32_16x16x32_bf16(a_h[r], b_l[c], acc[r][c], 0, 0, 0);
                acc[r][c] = __builtin_amdgcn_mfma_f32_16x16x32_bf16(a_l[r], b_h[c], acc[r][c], 0, 0, 0);
            }
        __syncthreads();
    }

    // ---- epilogue: raw bf16 h_{i+1} ----
    #pragma unroll
    for (int r = 0; r < 4; ++r) {
        #pragma unroll
        for (int c = 0; c < 2; ++c) {
            int gcol = wv * 32 + c * 16 + l15;
            #pragma unroll
            for (int j = 0; j < 4; ++j) {
                int grow = block_row + r * 16 + koct * 4 + j;
                if (grow < n) hout[(size_t)grow * F_OUT + gcol] = f2bf(acc[r][c][j]);
            }
        }
    }
}

// ---------------- final gather (layer 3, fp32 out) ----------------

__global__ __launch_bounds__(256) void gather_final(const ushort* __restrict__ hbf,
                                                    const int2* __restrict__ es,
                                                    const ull* __restrict__ slot,
                                                    const float* __restrict__ bias,
                                                    float* __restrict__ outf, int n) {
    int wave = threadIdx.x >> 6;
    int lane = threadIdx.x & 63;
    int node = blockIdx.x * 4 + wave;
    if (node >= n) return;

    int f = lane * 2;
    ull sl = slot[node];
    int cnt = (int)(sl >> 40);
    if (cnt > MAXDEG) cnt = MAXDEG;
    float dd = rsqrtf(1.0f + slot_sumw(sl));

    float2 r = gather_node(hbf, es + (size_t)node * MAXDEG, cnt, dd, node, f,
                           bias[f], bias[f + 1]);
    *reinterpret_cast<float2*>(&outf[(size_t)node * F_OUT + f]) = r;
}

// ---------------- launch ----------------

extern "C" void kernel_launch(void* const* d_in, const int* in_sizes, int n_in,
                              void* d_out, int out_size, void* d_ws, size_t ws_size,
                              hipStream_t stream) {
    const float* x  = (const float*)d_in[0];
    const int*   ei = (const int*)  d_in[1];
    const float* ew = (const float*)d_in[2];
    const float* W1 = (const float*)d_in[3];
    const float* b1 = (const float*)d_in[4];
    const float* W2 = (const float*)d_in[5];
    const float* b2 = (const float*)d_in[6];
    const float* W3 = (const float*)d_in[7];
    const float* b3 = (const float*)d_in[8];
    float* out = (float*)d_out;

    const int E = in_sizes[2];           // 800000
    const int n = in_sizes[0] / 256;     // 50000
    const int* src = ei;
    const int* dst = ei + E;

    // workspace layout (8B-aligned items first)
    char* ws = (char*)d_ws;
    ull*   slot  = (ull*)ws;                            // n
    int2*  es    = (int2*)(slot + n);                   // n*MAXDEG
    ushort* hbfA = (ushort*)(es + (size_t)n * MAXDEG);  // n*128 bf16
    ushort* hbfB = hbfA + (size_t)n * F_OUT;            // n*128 bf16
    ushort* W1th = hbfB + (size_t)n * F_OUT;            // 128*256
    ushort* W1tl = W1th + 128 * 256;
    ushort* W2th = W1tl + 128 * 256;                    // 128*128
    ushort* W2tl = W2th + 128 * 128;
    ushort* W3th = W2tl + 128 * 128;
    ushort* W3tl = W3th + 128 * 128;

    const int GB = (n + 63) / 64;        // 782 gemm blocks
    const int FB = (E + 127) / 128;      // 6250 fill blocks (1 edge/thread)
    const int prep_grid = 256 + (n + 127) / 128;

    // prep: wsplit(W1) || zero(slot)
    prep_kernel<<<prep_grid, 128, 0, stream>>>(W1, W1th, W1tl, slot, n);

    // mega1: GEMM1 || fill || wsplit(W2,W3) -> hbfA (raw h1)
    mega1_kernel<<<GB + FB + 256, 128, 0, stream>>>(
        x, W1th, W1tl, hbfA, src, dst, ew, slot, es,
        W2, W2th, W2tl, W3, W3th, W3tl, n, E, GB, FB);

    // coef (dis computed on the fly)
    coef_kernel<<<(n * MAXDEG + 255) / 256, 256, 0, stream>>>(es, slot, n);

    // layer 2: fused gather(h1)+GEMM(W2) -> hbfB (raw h2)
    fused_gg<<<GB, 256, 0, stream>>>(hbfA, es, slot, b1, W2th, W2tl, hbfB, n);

    // layer 3: fused gather(h2)+GEMM(W3) -> hbfA (raw h3)
    fused_gg<<<GB, 256, 0, stream>>>(hbfB, es, slot, b2, W3th, W3tl, hbfA, n);

    // final aggregate -> fp32 out
    gather_final<<<(n + 3) / 4, 256, 0, stream>>>(hbfA, es, slot, b3, out, n);
}

// Round 16
// 245.666 us; speedup vs baseline: 1.2006x; 1.2006x over previous
//
#include <hip/hip_runtime.h>
#include <math.h>

#define F_OUT 128
#define MAXDEG 64

typedef __attribute__((ext_vector_type(8))) short short8v;   // 8 bf16 (4 VGPR)
typedef __attribute__((ext_vector_type(4))) float f32x4;
typedef unsigned long long ull;

// ---- manual RNE fp32->bf16 (self-contained, finite inputs) ----
__device__ inline ushort f2bf(float x) {
    uint u = __float_as_uint(x);
    uint r = (u + 0x7FFFu + ((u >> 16) & 1u)) >> 16;
    return (ushort)r;
}
__device__ inline float bf2f(ushort h) { return __uint_as_float((uint)h << 16); }
__device__ inline uint pack2(ushort a, ushort b) { return (uint)a | ((uint)b << 16); }

__device__ inline float slot_sumw(ull s) {
    return (float)((double)(s & ((1ull << 40) - 1)) * (1.0 / 8388608.0));
}

// ---------------- prep: wsplit(W1) || zero(slot) ----------------

__global__ __launch_bounds__(128) void prep_kernel(const float* __restrict__ W1,
                                                   ushort* W1th, ushort* W1tl,
                                                   ull* slot, int n) {
    int b = blockIdx.x;
    if (b < 256) {                    // W1 split: 256*128 = 32768 elems
        int idx = b * 128 + threadIdx.x;
        int k = idx >> 7, c = idx & 127;
        float x = W1[idx];
        ushort h = f2bf(x);
        ushort l = f2bf(x - bf2f(h));
        W1th[(size_t)c * 256 + k] = h;
        W1tl[(size_t)c * 256 + k] = l;
    } else {
        int i = (b - 256) * 128 + threadIdx.x;
        if (i < n) slot[i] = 0ull;
    }
}

// ---------------- fill: one 64-bit atomic per edge ----------------
// slot[d] = (count << 40) | sum(w * 2^23)

__device__ __forceinline__ void fill_edge(const int* __restrict__ src,
                                          const int* __restrict__ dst,
                                          const float* __restrict__ w,
                                          ull* slot, int2* es, int e) {
    int s = src[e], d = dst[e];
    float wv = w[e];
    ull inc = (1ull << 40) | (ull)(uint)(wv * 8388608.0f + 0.5f);
    ull old = atomicAdd(&slot[d], inc);
    uint pos = (uint)(old >> 40);
    if (pos < MAXDEG) es[(size_t)d * MAXDEG + pos] = make_int2(s, __float_as_int(wv));
}

// coef: es.y = dis[src] * w, dis computed on the fly from slot
__global__ void coef_kernel(int2* es, const ull* __restrict__ slot, int n) {
    int i = blockIdx.x * blockDim.x + threadIdx.x;
    if (i < n * MAXDEG) {
        int d = i >> 6;                 // MAXDEG = 64
        int pos = i & (MAXDEG - 1);
        int cnt = (int)(slot[d] >> 40);
        if (pos < cnt) {
            int2 e = es[i];
            float dsrc = rsqrtf(1.0f + slot_sumw(slot[e.x]));
            es[i].y = __float_as_int(dsrc * __int_as_float(e.y));
        }
    }
}

// ---------------- GEMM body (layer 1): fp32 in, split in-kernel ----------------
// Split-bf16 3-product (hh + hl + lh), fp32 accumulate, bf16 output.
// BM=64, BN=128, BK=32; 128 threads = 2 waves; chunk-major LDS (conflict-free).

template <int K>
__device__ __forceinline__ void gemm_body(ushort* sAh, ushort* sAl,
                                          ushort* sBh, ushort* sBl,
                                          const float* __restrict__ in,
                                          const ushort* __restrict__ Wth,
                                          const ushort* __restrict__ Wtl,
                                          ushort* __restrict__ hbf, int n, int bb) {
    const int t = threadIdx.x;
    const int lane = t & 63;
    const int wv = t >> 6;
    const int block_row = bb * 64;

    const int arow = t >> 1;
    const int ahalf = t & 1;
    const int bcol = t;

    const int l15 = lane & 15;
    const int koct = lane >> 4;

    f32x4 acc[4][4];
    #pragma unroll
    for (int r = 0; r < 4; ++r)
        #pragma unroll
        for (int c = 0; c < 4; ++c) acc[r][c] = (f32x4){0.f, 0.f, 0.f, 0.f};

    const int grow_a = block_row + arow;
    const bool arow_ok = grow_a < n;

    for (int kt = 0; kt < K / 32; ++kt) {
        const int k0 = kt * 32;

        {
            float v[16];
            if (arow_ok) {
                const float4* p = reinterpret_cast<const float4*>(
                    &in[(size_t)grow_a * K + k0 + ahalf * 16]);
                float4 f0 = p[0], f1 = p[1], f2 = p[2], f3 = p[3];
                v[0]=f0.x; v[1]=f0.y; v[2]=f0.z; v[3]=f0.w;
                v[4]=f1.x; v[5]=f1.y; v[6]=f1.z; v[7]=f1.w;
                v[8]=f2.x; v[9]=f2.y; v[10]=f2.z; v[11]=f2.w;
                v[12]=f3.x; v[13]=f3.y; v[14]=f3.z; v[15]=f3.w;
            } else {
                #pragma unroll
                for (int i = 0; i < 16; ++i) v[i] = 0.f;
            }
            ushort hh[16], ll[16];
            #pragma unroll
            for (int i = 0; i < 16; ++i) {
                hh[i] = f2bf(v[i]);
                ll[i] = f2bf(v[i] - bf2f(hh[i]));
            }
            const int c0 = 2 * ahalf, c1 = 2 * ahalf + 1;
            *reinterpret_cast<uint4*>(&sAh[(c0 * 64 + arow) * 8]) =
                make_uint4(pack2(hh[0],hh[1]), pack2(hh[2],hh[3]), pack2(hh[4],hh[5]), pack2(hh[6],hh[7]));
            *reinterpret_cast<uint4*>(&sAh[(c1 * 64 + arow) * 8]) =
                make_uint4(pack2(hh[8],hh[9]), pack2(hh[10],hh[11]), pack2(hh[12],hh[13]), pack2(hh[14],hh[15]));
            *reinterpret_cast<uint4*>(&sAl[(c0 * 64 + arow) * 8]) =
                make_uint4(pack2(ll[0],ll[1]), pack2(ll[2],ll[3]), pack2(ll[4],ll[5]), pack2(ll[6],ll[7]));
            *reinterpret_cast<uint4*>(&sAl[(c1 * 64 + arow) * 8]) =
                make_uint4(pack2(ll[8],ll[9]), pack2(ll[10],ll[11]), pack2(ll[12],ll[13]), pack2(ll[14],ll[15]));
        }
        {
            const uint4* ph = reinterpret_cast<const uint4*>(&Wth[(size_t)bcol * K + k0]);
            const uint4* pl = reinterpret_cast<const uint4*>(&Wtl[(size_t)bcol * K + k0]);
            #pragma unroll
            for (int j = 0; j < 4; ++j)
                *reinterpret_cast<uint4*>(&sBh[(j * 128 + bcol) * 8]) = ph[j];
            #pragma unroll
            for (int j = 0; j < 4; ++j)
                *reinterpret_cast<uint4*>(&sBl[(j * 128 + bcol) * 8]) = pl[j];
        }
        __syncthreads();

        short8v a_h[4], a_l[4], b_h[4], b_l[4];
        #pragma unroll
        for (int r = 0; r < 4; ++r) {
            a_h[r] = *reinterpret_cast<const short8v*>(&sAh[(koct * 64 + r * 16 + l15) * 8]);
            a_l[r] = *reinterpret_cast<const short8v*>(&sAl[(koct * 64 + r * 16 + l15) * 8]);
        }
        #pragma unroll
        for (int c = 0; c < 4; ++c) {
            b_h[c] = *reinterpret_cast<const short8v*>(&sBh[(koct * 128 + wv * 64 + c * 16 + l15) * 8]);
            b_l[c] = *reinterpret_cast<const short8v*>(&sBl[(koct * 128 + wv * 64 + c * 16 + l15) * 8]);
        }
        #pragma unroll
        for (int r = 0; r < 4; ++r)
            #pragma unroll
            for (int c = 0; c < 4; ++c) {
                acc[r][c] = __builtin_amdgcn_mfma_f32_16x16x32_bf16(a_h[r], b_h[c], acc[r][c], 0, 0, 0);
                acc[r][c] = __builtin_amdgcn_mfma_f32_16x16x32_bf16(a_h[r], b_l[c], acc[r][c], 0, 0, 0);
                acc[r][c] = __builtin_amdgcn_mfma_f32_16x16x32_bf16(a_l[r], b_h[c], acc[r][c], 0, 0, 0);
            }
        __syncthreads();
    }

    // ---- epilogue: bf16 store ----
    #pragma unroll
    for (int r = 0; r < 4; ++r) {
        #pragma unroll
        for (int c = 0; c < 4; ++c) {
            int gcol = wv * 64 + c * 16 + l15;
            #pragma unroll
            for (int j = 0; j < 4; ++j) {
                int grow = block_row + r * 16 + koct * 4 + j;
                if (grow < n) hbf[(size_t)grow * F_OUT + gcol] = f2bf(acc[r][c][j]);
            }
        }
    }
}

// ---------------- GEMM (layers 2,3): pre-split A planes ----------------

template <int K>
__global__ __launch_bounds__(128) void gemm_presplit(const ushort* __restrict__ ahp,
                                                     const ushort* __restrict__ alp,
                                                     const ushort* __restrict__ Wth,
                                                     const ushort* __restrict__ Wtl,
                                                     ushort* __restrict__ hbf, int n) {
    __shared__ ushort sAh[64 * 32], sAl[64 * 32];
    __shared__ ushort sBh[128 * 32], sBl[128 * 32];

    const int t = threadIdx.x;
    const int lane = t & 63;
    const int wv = t >> 6;
    const int block_row = blockIdx.x * 64;

    const int arow = t >> 1;
    const int ahalf = t & 1;
    const int bcol = t;

    const int l15 = lane & 15;
    const int koct = lane >> 4;

    f32x4 acc[4][4];
    #pragma unroll
    for (int r = 0; r < 4; ++r)
        #pragma unroll
        for (int c = 0; c < 4; ++c) acc[r][c] = (f32x4){0.f, 0.f, 0.f, 0.f};

    const int grow_a = block_row + arow;
    const bool arow_ok = grow_a < n;
    const uint4 zero4 = make_uint4(0u, 0u, 0u, 0u);

    for (int kt = 0; kt < K / 32; ++kt) {
        const int k0 = kt * 32;
        const int c0 = 2 * ahalf, c1 = 2 * ahalf + 1;

        if (arow_ok) {
            const uint4* ph = reinterpret_cast<const uint4*>(&ahp[(size_t)grow_a * K + k0 + ahalf * 16]);
            const uint4* pl = reinterpret_cast<const uint4*>(&alp[(size_t)grow_a * K + k0 + ahalf * 16]);
            *reinterpret_cast<uint4*>(&sAh[(c0 * 64 + arow) * 8]) = ph[0];
            *reinterpret_cast<uint4*>(&sAh[(c1 * 64 + arow) * 8]) = ph[1];
            *reinterpret_cast<uint4*>(&sAl[(c0 * 64 + arow) * 8]) = pl[0];
            *reinterpret_cast<uint4*>(&sAl[(c1 * 64 + arow) * 8]) = pl[1];
        } else {
            *reinterpret_cast<uint4*>(&sAh[(c0 * 64 + arow) * 8]) = zero4;
            *reinterpret_cast<uint4*>(&sAh[(c1 * 64 + arow) * 8]) = zero4;
            *reinterpret_cast<uint4*>(&sAl[(c0 * 64 + arow) * 8]) = zero4;
            *reinterpret_cast<uint4*>(&sAl[(c1 * 64 + arow) * 8]) = zero4;
        }
        {
            const uint4* ph = reinterpret_cast<const uint4*>(&Wth[(size_t)bcol * K + k0]);
            const uint4* pl = reinterpret_cast<const uint4*>(&Wtl[(size_t)bcol * K + k0]);
            #pragma unroll
            for (int j = 0; j < 4; ++j)
                *reinterpret_cast<uint4*>(&sBh[(j * 128 + bcol) * 8]) = ph[j];
            #pragma unroll
            for (int j = 0; j < 4; ++j)
                *reinterpret_cast<uint4*>(&sBl[(j * 128 + bcol) * 8]) = pl[j];
        }
        __syncthreads();

        short8v a_h[4], a_l[4], b_h[4], b_l[4];
        #pragma unroll
        for (int r = 0; r < 4; ++r) {
            a_h[r] = *reinterpret_cast<const short8v*>(&sAh[(koct * 64 + r * 16 + l15) * 8]);
            a_l[r] = *reinterpret_cast<const short8v*>(&sAl[(koct * 64 + r * 16 + l15) * 8]);
        }
        #pragma unroll
        for (int c = 0; c < 4; ++c) {
            b_h[c] = *reinterpret_cast<const short8v*>(&sBh[(koct * 128 + wv * 64 + c * 16 + l15) * 8]);
            b_l[c] = *reinterpret_cast<const short8v*>(&sBl[(koct * 128 + wv * 64 + c * 16 + l15) * 8]);
        }
        #pragma unroll
        for (int r = 0; r < 4; ++r)
            #pragma unroll
            for (int c = 0; c < 4; ++c) {
                acc[r][c] = __builtin_amdgcn_mfma_f32_16x16x32_bf16(a_h[r], b_h[c], acc[r][c], 0, 0, 0);
                acc[r][c] = __builtin_amdgcn_mfma_f32_16x16x32_bf16(a_h[r], b_l[c], acc[r][c], 0, 0, 0);
                acc[r][c] = __builtin_amdgcn_mfma_f32_16x16x32_bf16(a_l[r], b_h[c], acc[r][c], 0, 0, 0);
            }
        __syncthreads();
    }

    #pragma unroll
    for (int r = 0; r < 4; ++r) {
        #pragma unroll
        for (int c = 0; c < 4; ++c) {
            int gcol = wv * 64 + c * 16 + l15;
            #pragma unroll
            for (int j = 0; j < 4; ++j) {
                int grow = block_row + r * 16 + koct * 4 + j;
                if (grow < n) hbf[(size_t)grow * F_OUT + gcol] = f2bf(acc[r][c][j]);
            }
        }
    }
}

// ---------------- mega1: fill(first) || GEMM1 || wsplit(W2,W3) ----------------
// Fill is the critical path (~52us vs GEMM1 ~30us): its blocks go FIRST in the
// grid so the latency-bound atomic stream starts immediately; GEMM blocks
// backfill CU slots and overlap on the MFMA pipe.

__global__ __launch_bounds__(128) void mega1_kernel(
        const float* __restrict__ x,
        const ushort* __restrict__ W1th, const ushort* __restrict__ W1tl,
        ushort* __restrict__ hbf,
        const int* __restrict__ src, const int* __restrict__ dst,
        const float* __restrict__ w, ull* slot, int2* es,
        const float* __restrict__ W2, ushort* W2th, ushort* W2tl,
        const float* __restrict__ W3, ushort* W3th, ushort* W3tl,
        int n, int E, int GB, int FB) {
    __shared__ ushort sAh[64 * 32], sAl[64 * 32];
    __shared__ ushort sBh[128 * 32], sBl[128 * 32];

    int b = blockIdx.x;
    if (b < FB) {
        int e = b * 128 + threadIdx.x;
        if (e < E) fill_edge(src, dst, w, slot, es, e);
    } else if (b < FB + GB) {
        gemm_body<256>(sAh, sAl, sBh, sBl, x, W1th, W1tl, hbf, n, b - FB);
    } else {
        int wb = b - FB - GB;          // 0..255: W2 then W3 (16384 elems each)
        const float* W = (wb < 128) ? W2 : W3;
        ushort* Th = (wb < 128) ? W2th : W3th;
        ushort* Tl = (wb < 128) ? W2tl : W3tl;
        int idx = (wb & 127) * 128 + threadIdx.x;
        int k = idx >> 7, c = idx & 127;
        float v = W[idx];
        ushort h = f2bf(v);
        ushort l = f2bf(v - bf2f(h));
        Th[(size_t)c * 128 + k] = h;
        Tl[(size_t)c * 128 + k] = l;
    }
}

// ---------------- gather ----------------
// acc = dis_d * (dis_d*h[d] + sum_e coef_e*h[s]) + bias; relu.
// One wave per node; lane owns 2 features; unroll-16 (16 row-loads in flight).

__device__ __forceinline__ void gacc(uint u, float c, float& ax, float& ay) {
    ax += c * __uint_as_float(u << 16);
    ay += c * __uint_as_float(u & 0xFFFF0000u);
}

template <bool SPLIT_OUT>
__global__ __launch_bounds__(256) void gather_kernel(const ushort* __restrict__ hbf,
                                                     const int2* __restrict__ es,
                                                     const ull* __restrict__ slot,
                                                     const float* __restrict__ bias,
                                                     ushort* __restrict__ oah,
                                                     ushort* __restrict__ oal,
                                                     float* __restrict__ outf, int n) {
    int wave = threadIdx.x >> 6;
    int lane = threadIdx.x & 63;
    int node = blockIdx.x * 4 + wave;
    if (node >= n) return;

    int f = lane * 2;
    ull sl = slot[node];
    int cnt = (int)(sl >> 40);
    if (cnt > MAXDEG) cnt = MAXDEG;
    float dd = rsqrtf(1.0f + slot_sumw(sl));

    uint hv = *reinterpret_cast<const uint*>(&hbf[(size_t)node * F_OUT + f]);
    float accx = dd * __uint_as_float(hv << 16);
    float accy = dd * __uint_as_float(hv & 0xFFFF0000u);

    const int2* ep = es + (size_t)node * MAXDEG;
    int i = 0;
    // 16-deep batch: 16 independent row-loads in flight per lane
    for (; i + 15 < cnt; i += 16) {
        int4 p[8];
        #pragma unroll
        for (int q = 0; q < 8; ++q) p[q] = *reinterpret_cast<const int4*>(&ep[i + 2 * q]);
        uint u[16];
        #pragma unroll
        for (int q = 0; q < 8; ++q) {
            u[2 * q]     = *reinterpret_cast<const uint*>(&hbf[(size_t)p[q].x * F_OUT + f]);
            u[2 * q + 1] = *reinterpret_cast<const uint*>(&hbf[(size_t)p[q].z * F_OUT + f]);
        }
        #pragma unroll
        for (int q = 0; q < 8; ++q) {
            gacc(u[2 * q],     __int_as_float(p[q].y), accx, accy);
            gacc(u[2 * q + 1], __int_as_float(p[q].w), accx, accy);
        }
    }
    for (; i + 7 < cnt; i += 8) {
        int4 p01 = *reinterpret_cast<const int4*>(&ep[i]);
        int4 p23 = *reinterpret_cast<const int4*>(&ep[i + 2]);
        int4 p45 = *reinterpret_cast<const int4*>(&ep[i + 4]);
        int4 p67 = *reinterpret_cast<const int4*>(&ep[i + 6]);
        uint u0 = *reinterpret_cast<const uint*>(&hbf[(size_t)p01.x * F_OUT + f]);
        uint u1 = *reinterpret_cast<const uint*>(&hbf[(size_t)p01.z * F_OUT + f]);
        uint u2 = *reinterpret_cast<const uint*>(&hbf[(size_t)p23.x * F_OUT + f]);
        uint u3 = *reinterpret_cast<const uint*>(&hbf[(size_t)p23.z * F_OUT + f]);
        uint u4 = *reinterpret_cast<const uint*>(&hbf[(size_t)p45.x * F_OUT + f]);
        uint u5 = *reinterpret_cast<const uint*>(&hbf[(size_t)p45.z * F_OUT + f]);
        uint u6 = *reinterpret_cast<const uint*>(&hbf[(size_t)p67.x * F_OUT + f]);
        uint u7 = *reinterpret_cast<const uint*>(&hbf[(size_t)p67.z * F_OUT + f]);
        gacc(u0, __int_as_float(p01.y), accx, accy);
        gacc(u1, __int_as_float(p01.w), accx, accy);
        gacc(u2, __int_as_float(p23.y), accx, accy);
        gacc(u3, __int_as_float(p23.w), accx, accy);
        gacc(u4, __int_as_float(p45.y), accx, accy);
        gacc(u5, __int_as_float(p45.w), accx, accy);
        gacc(u6, __int_as_float(p67.y), accx, accy);
        gacc(u7, __int_as_float(p67.w), accx, accy);
    }
    for (; i + 1 < cnt; i += 2) {
        int4 p01 = *reinterpret_cast<const int4*>(&ep[i]);
        uint u0 = *reinterpret_cast<const uint*>(&hbf[(size_t)p01.x * F_OUT + f]);
        uint u1 = *reinterpret_cast<const uint*>(&hbf[(size_t)p01.z * F_OUT + f]);
        gacc(u0, __int_as_float(p01.y), accx, accy);
        gacc(u1, __int_as_float(p01.w), accx, accy);
    }
    if (i < cnt) {
        int2 e0 = ep[i];
        uint u0 = *reinterpret_cast<const uint*>(&hbf[(size_t)e0.x * F_OUT + f]);
        gacc(u0, __int_as_float(e0.y), accx, accy);
    }

    float rx = fmaxf(bias[f]     + dd * accx, 0.f);
    float ry = fmaxf(bias[f + 1] + dd * accy, 0.f);

    if (SPLIT_OUT) {
        ushort hx = f2bf(rx), hy = f2bf(ry);
        ushort lx = f2bf(rx - bf2f(hx)), ly = f2bf(ry - bf2f(hy));
        *reinterpret_cast<uint*>(&oah[(size_t)node * F_OUT + f]) = pack2(hx, hy);
        *reinterpret_cast<uint*>(&oal[(size_t)node * F_OUT + f]) = pack2(lx, ly);
    } else {
        *reinterpret_cast<float2*>(&outf[(size_t)node * F_OUT + f]) = make_float2(rx, ry);
    }
}

// ---------------- launch ----------------

extern "C" void kernel_launch(void* const* d_in, const int* in_sizes, int n_in,
                              void* d_out, int out_size, void* d_ws, size_t ws_size,
                              hipStream_t stream) {
    const float* x  = (const float*)d_in[0];
    const int*   ei = (const int*)  d_in[1];
    const float* ew = (const float*)d_in[2];
    const float* W1 = (const float*)d_in[3];
    const float* b1 = (const float*)d_in[4];
    const float* W2 = (const float*)d_in[5];
    const float* b2 = (const float*)d_in[6];
    const float* W3 = (const float*)d_in[7];
    const float* b3 = (const float*)d_in[8];
    float* out = (float*)d_out;

    const int E = in_sizes[2];           // 800000
    const int n = in_sizes[0] / 256;     // 50000
    const int* src = ei;
    const int* dst = ei + E;

    // workspace layout (8B-aligned items first)
    char* ws = (char*)d_ws;
    ull*   slot  = (ull*)ws;                           // n
    int2*  es    = (int2*)(slot + n);                  // n*MAXDEG
    ushort* hbf  = (ushort*)(es + (size_t)n * MAXDEG); // n*128 bf16
    ushort* aah  = hbf + (size_t)n * F_OUT;            // n*128 act hi
    ushort* aal  = aah + (size_t)n * F_OUT;            // n*128 act lo
    ushort* W1th = aal + (size_t)n * F_OUT;            // 128*256
    ushort* W1tl = W1th + 128 * 256;
    ushort* W2th = W1tl + 128 * 256;                   // 128*128
    ushort* W2tl = W2th + 128 * 128;
    ushort* W3th = W2tl + 128 * 128;
    ushort* W3tl = W3th + 128 * 128;

    const int GB = (n + 63) / 64;        // 782 gemm blocks
    const int FB = (E + 127) / 128;      // 6250 fill blocks (1 edge/thread)
    const int prep_grid = 256 + (n + 127) / 128;

    // prep: wsplit(W1) || zero(slot)
    prep_kernel<<<prep_grid, 128, 0, stream>>>(W1, W1th, W1tl, slot, n);

    // mega1: fill || GEMM1 || wsplit(W2,W3)  (fill blocks first)
    mega1_kernel<<<FB + GB + 256, 128, 0, stream>>>(
        x, W1th, W1tl, hbf, src, dst, ew, slot, es,
        W2, W2th, W2tl, W3, W3th, W3tl, n, E, GB, FB);

    // coef (dis computed on the fly)
    coef_kernel<<<(n * MAXDEG + 255) / 256, 256, 0, stream>>>(es, slot, n);

    const int gather_grid = (n + 3) / 4;

    // layer 1 aggregate -> split act planes
    gather_kernel<true><<<gather_grid, 256, 0, stream>>>(hbf, es, slot, b1, aah, aal, nullptr, n);

    // layer 2
    gemm_presplit<128><<<GB, 128, 0, stream>>>(aah, aal, W2th, W2tl, hbf, n);
    gather_kernel<true><<<gather_grid, 256, 0, stream>>>(hbf, es, slot, b2, aah, aal, nullptr, n);

    // layer 3
    gemm_presplit<128><<<GB, 128, 0, stream>>>(aah, aal, W3th, W3tl, hbf, n);
    gather_kernel<false><<<gather_grid, 256, 0, stream>>>(hbf, es, slot, b3, nullptr, nullptr, out, n);
}

// Round 17
// 207.728 us; speedup vs baseline: 1.4199x; 1.1826x over previous
//
#include <hip/hip_runtime.h>
#include <math.h>

#define F_OUT 128
#define MAXDEG 64

typedef __attribute__((ext_vector_type(8))) short short8v;   // 8 bf16 (4 VGPR)
typedef __attribute__((ext_vector_type(4))) float f32x4;
typedef unsigned long long ull;

// ---- manual RNE fp32->bf16 (self-contained, finite inputs) ----
__device__ inline ushort f2bf(float x) {
    uint u = __float_as_uint(x);
    uint r = (u + 0x7FFFu + ((u >> 16) & 1u)) >> 16;
    return (ushort)r;
}
__device__ inline float bf2f(ushort h) { return __uint_as_float((uint)h << 16); }
__device__ inline uint pack2(ushort a, ushort b) { return (uint)a | ((uint)b << 16); }

__device__ inline float slot_sumw(ull s) {
    return (float)((double)(s & ((1ull << 40) - 1)) * (1.0 / 8388608.0));
}

// ---------------- prep: wsplit(W1) || zero(slot) ----------------

__global__ __launch_bounds__(128) void prep_kernel(const float* __restrict__ W1,
                                                   ushort* W1th, ushort* W1tl,
                                                   ull* slot, int n) {
    int b = blockIdx.x;
    if (b < 256) {                    // W1 split: 256*128 = 32768 elems
        int idx = b * 128 + threadIdx.x;
        int k = idx >> 7, c = idx & 127;
        float x = W1[idx];
        ushort h = f2bf(x);
        ushort l = f2bf(x - bf2f(h));
        W1th[(size_t)c * 256 + k] = h;
        W1tl[(size_t)c * 256 + k] = l;
    } else {
        int i = (b - 256) * 128 + threadIdx.x;
        if (i < n) slot[i] = 0ull;
    }
}

// ---------------- fill: one 64-bit atomic per edge ----------------
// slot[d] = (count << 40) | sum(w * 2^23)

__device__ __forceinline__ void fill_edge(const int* __restrict__ src,
                                          const int* __restrict__ dst,
                                          const float* __restrict__ w,
                                          ull* slot, int2* es, int e) {
    int s = src[e], d = dst[e];
    float wv = w[e];
    ull inc = (1ull << 40) | (ull)(uint)(wv * 8388608.0f + 0.5f);
    ull old = atomicAdd(&slot[d], inc);
    uint pos = (uint)(old >> 40);
    if (pos < MAXDEG) es[(size_t)d * MAXDEG + pos] = make_int2(s, __float_as_int(wv));
}

// coef: es.y = dis[src] * w, dis computed on the fly from slot
__global__ void coef_kernel(int2* es, const ull* __restrict__ slot, int n) {
    int i = blockIdx.x * blockDim.x + threadIdx.x;
    if (i < n * MAXDEG) {
        int d = i >> 6;                 // MAXDEG = 64
        int pos = i & (MAXDEG - 1);
        int cnt = (int)(slot[d] >> 40);
        if (pos < cnt) {
            int2 e = es[i];
            float dsrc = rsqrtf(1.0f + slot_sumw(slot[e.x]));
            es[i].y = __float_as_int(dsrc * __int_as_float(e.y));
        }
    }
}

// ---------------- GEMM body (layer 1): fp32 in, split in-kernel ----------------
// Split-bf16 3-product (hh + hl + lh), fp32 accumulate, bf16 output.
// BM=64, BN=128, BK=32; 128 threads = 2 waves; chunk-major LDS (conflict-free).

template <int K>
__device__ __forceinline__ void gemm_body(ushort* sAh, ushort* sAl,
                                          ushort* sBh, ushort* sBl,
                                          const float* __restrict__ in,
                                          const ushort* __restrict__ Wth,
                                          const ushort* __restrict__ Wtl,
                                          ushort* __restrict__ hbf, int n, int bb) {
    const int t = threadIdx.x;
    const int lane = t & 63;
    const int wv = t >> 6;
    const int block_row = bb * 64;

    const int arow = t >> 1;
    const int ahalf = t & 1;
    const int bcol = t;

    const int l15 = lane & 15;
    const int koct = lane >> 4;

    f32x4 acc[4][4];
    #pragma unroll
    for (int r = 0; r < 4; ++r)
        #pragma unroll
        for (int c = 0; c < 4; ++c) acc[r][c] = (f32x4){0.f, 0.f, 0.f, 0.f};

    const int grow_a = block_row + arow;
    const bool arow_ok = grow_a < n;

    for (int kt = 0; kt < K / 32; ++kt) {
        const int k0 = kt * 32;

        {
            float v[16];
            if (arow_ok) {
                const float4* p = reinterpret_cast<const float4*>(
                    &in[(size_t)grow_a * K + k0 + ahalf * 16]);
                float4 f0 = p[0], f1 = p[1], f2 = p[2], f3 = p[3];
                v[0]=f0.x; v[1]=f0.y; v[2]=f0.z; v[3]=f0.w;
                v[4]=f1.x; v[5]=f1.y; v[6]=f1.z; v[7]=f1.w;
                v[8]=f2.x; v[9]=f2.y; v[10]=f2.z; v[11]=f2.w;
                v[12]=f3.x; v[13]=f3.y; v[14]=f3.z; v[15]=f3.w;
            } else {
                #pragma unroll
                for (int i = 0; i < 16; ++i) v[i] = 0.f;
            }
            ushort hh[16], ll[16];
            #pragma unroll
            for (int i = 0; i < 16; ++i) {
                hh[i] = f2bf(v[i]);
                ll[i] = f2bf(v[i] - bf2f(hh[i]));
            }
            const int c0 = 2 * ahalf, c1 = 2 * ahalf + 1;
            *reinterpret_cast<uint4*>(&sAh[(c0 * 64 + arow) * 8]) =
                make_uint4(pack2(hh[0],hh[1]), pack2(hh[2],hh[3]), pack2(hh[4],hh[5]), pack2(hh[6],hh[7]));
            *reinterpret_cast<uint4*>(&sAh[(c1 * 64 + arow) * 8]) =
                make_uint4(pack2(hh[8],hh[9]), pack2(hh[10],hh[11]), pack2(hh[12],hh[13]), pack2(hh[14],hh[15]));
            *reinterpret_cast<uint4*>(&sAl[(c0 * 64 + arow) * 8]) =
                make_uint4(pack2(ll[0],ll[1]), pack2(ll[2],ll[3]), pack2(ll[4],ll[5]), pack2(ll[6],ll[7]));
            *reinterpret_cast<uint4*>(&sAl[(c1 * 64 + arow) * 8]) =
                make_uint4(pack2(ll[8],ll[9]), pack2(ll[10],ll[11]), pack2(ll[12],ll[13]), pack2(ll[14],ll[15]));
        }
        {
            const uint4* ph = reinterpret_cast<const uint4*>(&Wth[(size_t)bcol * K + k0]);
            const uint4* pl = reinterpret_cast<const uint4*>(&Wtl[(size_t)bcol * K + k0]);
            #pragma unroll
            for (int j = 0; j < 4; ++j)
                *reinterpret_cast<uint4*>(&sBh[(j * 128 + bcol) * 8]) = ph[j];
            #pragma unroll
            for (int j = 0; j < 4; ++j)
                *reinterpret_cast<uint4*>(&sBl[(j * 128 + bcol) * 8]) = pl[j];
        }
        __syncthreads();

        short8v a_h[4], a_l[4], b_h[4], b_l[4];
        #pragma unroll
        for (int r = 0; r < 4; ++r) {
            a_h[r] = *reinterpret_cast<const short8v*>(&sAh[(koct * 64 + r * 16 + l15) * 8]);
            a_l[r] = *reinterpret_cast<const short8v*>(&sAl[(koct * 64 + r * 16 + l15) * 8]);
        }
        #pragma unroll
        for (int c = 0; c < 4; ++c) {
            b_h[c] = *reinterpret_cast<const short8v*>(&sBh[(koct * 128 + wv * 64 + c * 16 + l15) * 8]);
            b_l[c] = *reinterpret_cast<const short8v*>(&sBl[(koct * 128 + wv * 64 + c * 16 + l15) * 8]);
        }
        #pragma unroll
        for (int r = 0; r < 4; ++r)
            #pragma unroll
            for (int c = 0; c < 4; ++c) {
                acc[r][c] = __builtin_amdgcn_mfma_f32_16x16x32_bf16(a_h[r], b_h[c], acc[r][c], 0, 0, 0);
                acc[r][c] = __builtin_amdgcn_mfma_f32_16x16x32_bf16(a_h[r], b_l[c], acc[r][c], 0, 0, 0);
                acc[r][c] = __builtin_amdgcn_mfma_f32_16x16x32_bf16(a_l[r], b_h[c], acc[r][c], 0, 0, 0);
            }
        __syncthreads();
    }

    // ---- epilogue: bf16 store ----
    #pragma unroll
    for (int r = 0; r < 4; ++r) {
        #pragma unroll
        for (int c = 0; c < 4; ++c) {
            int gcol = wv * 64 + c * 16 + l15;
            #pragma unroll
            for (int j = 0; j < 4; ++j) {
                int grow = block_row + r * 16 + koct * 4 + j;
                if (grow < n) hbf[(size_t)grow * F_OUT + gcol] = f2bf(acc[r][c][j]);
            }
        }
    }
}

// ---------------- GEMM (layers 2,3): pre-split A planes ----------------

template <int K>
__global__ __launch_bounds__(128) void gemm_presplit(const ushort* __restrict__ ahp,
                                                     const ushort* __restrict__ alp,
                                                     const ushort* __restrict__ Wth,
                                                     const ushort* __restrict__ Wtl,
                                                     ushort* __restrict__ hbf, int n) {
    __shared__ ushort sAh[64 * 32], sAl[64 * 32];
    __shared__ ushort sBh[128 * 32], sBl[128 * 32];

    const int t = threadIdx.x;
    const int lane = t & 63;
    const int wv = t >> 6;
    const int block_row = blockIdx.x * 64;

    const int arow = t >> 1;
    const int ahalf = t & 1;
    const int bcol = t;

    const int l15 = lane & 15;
    const int koct = lane >> 4;

    f32x4 acc[4][4];
    #pragma unroll
    for (int r = 0; r < 4; ++r)
        #pragma unroll
        for (int c = 0; c < 4; ++c) acc[r][c] = (f32x4){0.f, 0.f, 0.f, 0.f};

    const int grow_a = block_row + arow;
    const bool arow_ok = grow_a < n;
    const uint4 zero4 = make_uint4(0u, 0u, 0u, 0u);

    for (int kt = 0; kt < K / 32; ++kt) {
        const int k0 = kt * 32;
        const int c0 = 2 * ahalf, c1 = 2 * ahalf + 1;

        if (arow_ok) {
            const uint4* ph = reinterpret_cast<const uint4*>(&ahp[(size_t)grow_a * K + k0 + ahalf * 16]);
            const uint4* pl = reinterpret_cast<const uint4*>(&alp[(size_t)grow_a * K + k0 + ahalf * 16]);
            *reinterpret_cast<uint4*>(&sAh[(c0 * 64 + arow) * 8]) = ph[0];
            *reinterpret_cast<uint4*>(&sAh[(c1 * 64 + arow) * 8]) = ph[1];
            *reinterpret_cast<uint4*>(&sAl[(c0 * 64 + arow) * 8]) = pl[0];
            *reinterpret_cast<uint4*>(&sAl[(c1 * 64 + arow) * 8]) = pl[1];
        } else {
            *reinterpret_cast<uint4*>(&sAh[(c0 * 64 + arow) * 8]) = zero4;
            *reinterpret_cast<uint4*>(&sAh[(c1 * 64 + arow) * 8]) = zero4;
            *reinterpret_cast<uint4*>(&sAl[(c0 * 64 + arow) * 8]) = zero4;
            *reinterpret_cast<uint4*>(&sAl[(c1 * 64 + arow) * 8]) = zero4;
        }
        {
            const uint4* ph = reinterpret_cast<const uint4*>(&Wth[(size_t)bcol * K + k0]);
            const uint4* pl = reinterpret_cast<const uint4*>(&Wtl[(size_t)bcol * K + k0]);
            #pragma unroll
            for (int j = 0; j < 4; ++j)
                *reinterpret_cast<uint4*>(&sBh[(j * 128 + bcol) * 8]) = ph[j];
            #pragma unroll
            for (int j = 0; j < 4; ++j)
                *reinterpret_cast<uint4*>(&sBl[(j * 128 + bcol) * 8]) = pl[j];
        }
        __syncthreads();

        short8v a_h[4], a_l[4], b_h[4], b_l[4];
        #pragma unroll
        for (int r = 0; r < 4; ++r) {
            a_h[r] = *reinterpret_cast<const short8v*>(&sAh[(koct * 64 + r * 16 + l15) * 8]);
            a_l[r] = *reinterpret_cast<const short8v*>(&sAl[(koct * 64 + r * 16 + l15) * 8]);
        }
        #pragma unroll
        for (int c = 0; c < 4; ++c) {
            b_h[c] = *reinterpret_cast<const short8v*>(&sBh[(koct * 128 + wv * 64 + c * 16 + l15) * 8]);
            b_l[c] = *reinterpret_cast<const short8v*>(&sBl[(koct * 128 + wv * 64 + c * 16 + l15) * 8]);
        }
        #pragma unroll
        for (int r = 0; r < 4; ++r)
            #pragma unroll
            for (int c = 0; c < 4; ++c) {
                acc[r][c] = __builtin_amdgcn_mfma_f32_16x16x32_bf16(a_h[r], b_h[c], acc[r][c], 0, 0, 0);
                acc[r][c] = __builtin_amdgcn_mfma_f32_16x16x32_bf16(a_h[r], b_l[c], acc[r][c], 0, 0, 0);
                acc[r][c] = __builtin_amdgcn_mfma_f32_16x16x32_bf16(a_l[r], b_h[c], acc[r][c], 0, 0, 0);
            }
        __syncthreads();
    }

    #pragma unroll
    for (int r = 0; r < 4; ++r) {
        #pragma unroll
        for (int c = 0; c < 4; ++c) {
            int gcol = wv * 64 + c * 16 + l15;
            #pragma unroll
            for (int j = 0; j < 4; ++j) {
                int grow = block_row + r * 16 + koct * 4 + j;
                if (grow < n) hbf[(size_t)grow * F_OUT + gcol] = f2bf(acc[r][c][j]);
            }
        }
    }
}

// ---------------- mega1: GEMM1 || fill(1 edge/thread) || wsplit(W2,W3) ----------------
// GEMM blocks FIRST (measured best: r13/14 vs r9 prologue-fusion and r16
// fill-first both regressed): GEMM grabs CUs, fill backfills freed slots.

__global__ __launch_bounds__(128) void mega1_kernel(
        const float* __restrict__ x,
        const ushort* __restrict__ W1th, const ushort* __restrict__ W1tl,
        ushort* __restrict__ hbf,
        const int* __restrict__ src, const int* __restrict__ dst,
        const float* __restrict__ w, ull* slot, int2* es,
        const float* __restrict__ W2, ushort* W2th, ushort* W2tl,
        const float* __restrict__ W3, ushort* W3th, ushort* W3tl,
        int n, int E, int GB, int FB) {
    __shared__ ushort sAh[64 * 32], sAl[64 * 32];
    __shared__ ushort sBh[128 * 32], sBl[128 * 32];

    int b = blockIdx.x;
    if (b < GB) {
        gemm_body<256>(sAh, sAl, sBh, sBl, x, W1th, W1tl, hbf, n, b);
    } else if (b < GB + FB) {
        int e = (b - GB) * 128 + threadIdx.x;
        if (e < E) fill_edge(src, dst, w, slot, es, e);
    } else {
        int wb = b - GB - FB;          // 0..255: W2 then W3 (16384 elems each)
        const float* W = (wb < 128) ? W2 : W3;
        ushort* Th = (wb < 128) ? W2th : W3th;
        ushort* Tl = (wb < 128) ? W2tl : W3tl;
        int idx = (wb & 127) * 128 + threadIdx.x;
        int k = idx >> 7, c = idx & 127;
        float v = W[idx];
        ushort h = f2bf(v);
        ushort l = f2bf(v - bf2f(h));
        Th[(size_t)c * 128 + k] = h;
        Tl[(size_t)c * 128 + k] = l;
    }
}

// ---------------- gather ----------------
// acc = dis_d * (dis_d*h[d] + sum_e coef_e*h[s]) + bias; relu.
// One wave per node; lane owns 2 features; unroll-16 (16 row-loads in flight).

__device__ __forceinline__ void gacc(uint u, float c, float& ax, float& ay) {
    ax += c * __uint_as_float(u << 16);
    ay += c * __uint_as_float(u & 0xFFFF0000u);
}

template <bool SPLIT_OUT>
__global__ __launch_bounds__(256) void gather_kernel(const ushort* __restrict__ hbf,
                                                     const int2* __restrict__ es,
                                                     const ull* __restrict__ slot,
                                                     const float* __restrict__ bias,
                                                     ushort* __restrict__ oah,
                                                     ushort* __restrict__ oal,
                                                     float* __restrict__ outf, int n) {
    int wave = threadIdx.x >> 6;
    int lane = threadIdx.x & 63;
    int node = blockIdx.x * 4 + wave;
    if (node >= n) return;

    int f = lane * 2;
    ull sl = slot[node];
    int cnt = (int)(sl >> 40);
    if (cnt > MAXDEG) cnt = MAXDEG;
    float dd = rsqrtf(1.0f + slot_sumw(sl));

    uint hv = *reinterpret_cast<const uint*>(&hbf[(size_t)node * F_OUT + f]);
    float accx = dd * __uint_as_float(hv << 16);
    float accy = dd * __uint_as_float(hv & 0xFFFF0000u);

    const int2* ep = es + (size_t)node * MAXDEG;
    int i = 0;
    // 16-deep batch: 16 independent row-loads in flight per lane
    for (; i + 15 < cnt; i += 16) {
        int4 p[8];
        #pragma unroll
        for (int q = 0; q < 8; ++q) p[q] = *reinterpret_cast<const int4*>(&ep[i + 2 * q]);
        uint u[16];
        #pragma unroll
        for (int q = 0; q < 8; ++q) {
            u[2 * q]     = *reinterpret_cast<const uint*>(&hbf[(size_t)p[q].x * F_OUT + f]);
            u[2 * q + 1] = *reinterpret_cast<const uint*>(&hbf[(size_t)p[q].z * F_OUT + f]);
        }
        #pragma unroll
        for (int q = 0; q < 8; ++q) {
            gacc(u[2 * q],     __int_as_float(p[q].y), accx, accy);
            gacc(u[2 * q + 1], __int_as_float(p[q].w), accx, accy);
        }
    }
    for (; i + 7 < cnt; i += 8) {
        int4 p01 = *reinterpret_cast<const int4*>(&ep[i]);
        int4 p23 = *reinterpret_cast<const int4*>(&ep[i + 2]);
        int4 p45 = *reinterpret_cast<const int4*>(&ep[i + 4]);
        int4 p67 = *reinterpret_cast<const int4*>(&ep[i + 6]);
        uint u0 = *reinterpret_cast<const uint*>(&hbf[(size_t)p01.x * F_OUT + f]);
        uint u1 = *reinterpret_cast<const uint*>(&hbf[(size_t)p01.z * F_OUT + f]);
        uint u2 = *reinterpret_cast<const uint*>(&hbf[(size_t)p23.x * F_OUT + f]);
        uint u3 = *reinterpret_cast<const uint*>(&hbf[(size_t)p23.z * F_OUT + f]);
        uint u4 = *reinterpret_cast<const uint*>(&hbf[(size_t)p45.x * F_OUT + f]);
        uint u5 = *reinterpret_cast<const uint*>(&hbf[(size_t)p45.z * F_OUT + f]);
        uint u6 = *reinterpret_cast<const uint*>(&hbf[(size_t)p67.x * F_OUT + f]);
        uint u7 = *reinterpret_cast<const uint*>(&hbf[(size_t)p67.z * F_OUT + f]);
        gacc(u0, __int_as_float(p01.y), accx, accy);
        gacc(u1, __int_as_float(p01.w), accx, accy);
        gacc(u2, __int_as_float(p23.y), accx, accy);
        gacc(u3, __int_as_float(p23.w), accx, accy);
        gacc(u4, __int_as_float(p45.y), accx, accy);
        gacc(u5, __int_as_float(p45.w), accx, accy);
        gacc(u6, __int_as_float(p67.y), accx, accy);
        gacc(u7, __int_as_float(p67.w), accx, accy);
    }
    for (; i + 1 < cnt; i += 2) {
        int4 p01 = *reinterpret_cast<const int4*>(&ep[i]);
        uint u0 = *reinterpret_cast<const uint*>(&hbf[(size_t)p01.x * F_OUT + f]);
        uint u1 = *reinterpret_cast<const uint*>(&hbf[(size_t)p01.z * F_OUT + f]);
        gacc(u0, __int_as_float(p01.y), accx, accy);
        gacc(u1, __int_as_float(p01.w), accx, accy);
    }
    if (i < cnt) {
        int2 e0 = ep[i];
        uint u0 = *reinterpret_cast<const uint*>(&hbf[(size_t)e0.x * F_OUT + f]);
        gacc(u0, __int_as_float(e0.y), accx, accy);
    }

    float rx = fmaxf(bias[f]     + dd * accx, 0.f);
    float ry = fmaxf(bias[f + 1] + dd * accy, 0.f);

    if (SPLIT_OUT) {
        ushort hx = f2bf(rx), hy = f2bf(ry);
        ushort lx = f2bf(rx - bf2f(hx)), ly = f2bf(ry - bf2f(hy));
        *reinterpret_cast<uint*>(&oah[(size_t)node * F_OUT + f]) = pack2(hx, hy);
        *reinterpret_cast<uint*>(&oal[(size_t)node * F_OUT + f]) = pack2(lx, ly);
    } else {
        *reinterpret_cast<float2*>(&outf[(size_t)node * F_OUT + f]) = make_float2(rx, ry);
    }
}

// ---------------- launch ----------------

extern "C" void kernel_launch(void* const* d_in, const int* in_sizes, int n_in,
                              void* d_out, int out_size, void* d_ws, size_t ws_size,
                              hipStream_t stream) {
    const float* x  = (const float*)d_in[0];
    const int*   ei = (const int*)  d_in[1];
    const float* ew = (const float*)d_in[2];
    const float* W1 = (const float*)d_in[3];
    const float* b1 = (const float*)d_in[4];
    const float* W2 = (const float*)d_in[5];
    const float* b2 = (const float*)d_in[6];
    const float* W3 = (const float*)d_in[7];
    const float* b3 = (const float*)d_in[8];
    float* out = (float*)d_out;

    const int E = in_sizes[2];           // 800000
    const int n = in_sizes[0] / 256;     // 50000
    const int* src = ei;
    const int* dst = ei + E;

    // workspace layout (8B-aligned items first)
    char* ws = (char*)d_ws;
    ull*   slot  = (ull*)ws;                           // n
    int2*  es    = (int2*)(slot + n);                  // n*MAXDEG
    ushort* hbf  = (ushort*)(es + (size_t)n * MAXDEG); // n*128 bf16
    ushort* aah  = hbf + (size_t)n * F_OUT;            // n*128 act hi
    ushort* aal  = aah + (size_t)n * F_OUT;            // n*128 act lo
    ushort* W1th = aal + (size_t)n * F_OUT;            // 128*256
    ushort* W1tl = W1th + 128 * 256;
    ushort* W2th = W1tl + 128 * 256;                   // 128*128
    ushort* W2tl = W2th + 128 * 128;
    ushort* W3th = W2tl + 128 * 128;
    ushort* W3tl = W3th + 128 * 128;

    const int GB = (n + 63) / 64;        // 782 gemm blocks
    const int FB = (E + 127) / 128;      // 6250 fill blocks (1 edge/thread)
    const int prep_grid = 256 + (n + 127) / 128;

    // prep: wsplit(W1) || zero(slot)
    prep_kernel<<<prep_grid, 128, 0, stream>>>(W1, W1th, W1tl, slot, n);

    // mega1: GEMM1 || fill || wsplit(W2,W3)
    mega1_kernel<<<GB + FB + 256, 128, 0, stream>>>(
        x, W1th, W1tl, hbf, src, dst, ew, slot, es,
        W2, W2th, W2tl, W3, W3th, W3tl, n, E, GB, FB);

    // coef (dis computed on the fly)
    coef_kernel<<<(n * MAXDEG + 255) / 256, 256, 0, stream>>>(es, slot, n);

    const int gather_grid = (n + 3) / 4;

    // layer 1 aggregate -> split act planes
    gather_kernel<true><<<gather_grid, 256, 0, stream>>>(hbf, es, slot, b1, aah, aal, nullptr, n);

    // layer 2
    gemm_presplit<128><<<GB, 128, 0, stream>>>(aah, aal, W2th, W2tl, hbf, n);
    gather_kernel<true><<<gather_grid, 256, 0, stream>>>(hbf, es, slot, b2, aah, aal, nullptr, n);

    // layer 3
    gemm_presplit<128><<<GB, 128, 0, stream>>>(aah, aal, W3th, W3tl, hbf, n);
    gather_kernel<false><<<gather_grid, 256, 0, stream>>>(hbf, es, slot, b3, nullptr, nullptr, out, n);
}